// Round 1
// baseline (6311.781 us; speedup 1.0000x reference)
//
#include <hip/hip_runtime.h>
#include <hip/hip_bf16.h>

typedef short bf16x8 __attribute__((ext_vector_type(8)));
typedef float f32x4  __attribute__((ext_vector_type(4)));

#define B_   64
#define T_   512
#define XD_  256
#define H_   1024
#define KT_  1280   // 256 (x) + 1024 (h)

// workspace layout (bytes)
#define OFF_WCAT  0UL
#define SZ_WCAT   (3072UL*KT_*2)            // 7,864,320
#define OFF_XB    (OFF_WCAT + SZ_WCAT)
#define SZ_XB     (512UL*64*256*2)          // 16,777,216
#define OFF_RING  (OFF_XB + SZ_XB)
#define SZ_RING   (16UL*64*1024*4)          // 4,194,304
#define OFF_HBF32 (OFF_RING + SZ_RING)
#define SZ_HBF32  (2UL*64*1024*4)
#define OFF_HBF16 (OFF_HBF32 + SZ_HBF32)
#define SZ_HBF16  (2UL*64*1024*2)
#define OFF_ALPHA (OFF_HBF16 + SZ_HBF16)
#define OFF_BETA  (OFF_ALPHA + 4096)
#define OFF_LAG   (OFF_BETA  + 4096)

__device__ __forceinline__ float sigm_(float x) { return 1.f / (1.f + __expf(-x)); }
__device__ __forceinline__ float tanh_(float x) { return 1.f - 2.f / (__expf(2.f * x) + 1.f); }
__device__ __forceinline__ short bf16_of(float f) {
    __hip_bfloat16 h = __float2bfloat16(f);
    return *reinterpret_cast<short*>(&h);
}

// ---- prep: concat W_ih|W_hh into bf16 Wcat[3072][1280] ----
__global__ void prep_wcat(const float* __restrict__ W_ih, const float* __restrict__ W_hh,
                          short* __restrict__ Wcat) {
    const int j = blockIdx.x;              // 0..3071
    for (int k = threadIdx.x; k < KT_; k += 256) {
        float v = (k < XD_) ? W_ih[j * XD_ + k] : W_hh[j * H_ + (k - XD_)];
        Wcat[(long)j * KT_ + k] = bf16_of(v);
    }
}

// ---- prep: transpose x [B][T][X] f32 -> xb [T][B][X] bf16 ----
__global__ void prep_xb(const float* __restrict__ x, short* __restrict__ xb) {
    const long total = (long)T_ * B_ * XD_;
    for (long i = (long)blockIdx.x * blockDim.x + threadIdx.x; i < total;
         i += (long)gridDim.x * blockDim.x) {
        int t   = (int)(i >> 14);          // /(64*256)
        int rem = (int)(i & 16383);
        int b   = rem >> 8;
        int k   = rem & 255;
        xb[i] = bf16_of(x[((long)(b * T_ + t)) * XD_ + k]);
    }
}

// ---- prep: per-step skip plan ----
__global__ void prep_plan(const int* __restrict__ w1, const int* __restrict__ w2,
                          const int* __restrict__ ssp,
                          float* __restrict__ alphas, float* __restrict__ betas,
                          int* __restrict__ lags) {
    int t = threadIdx.x;
    if (t > T_) return;
    int ss = ssp[0];
    if (t == T_) { alphas[t] = 0.f; betas[t] = 0.f; lags[t] = 1; return; }
    float a = (float)w1[t];
    int uz = 0, slot = 0;
    if (t < ss)            { if (2 * t < ss) uz = 1; else slot = ss - t - 1; }
    else if (t - ss < ss)  { uz = 1; }
    else                   { slot = 2 * ss - 1; }
    alphas[t] = a;
    betas[t]  = uz ? 0.f : (float)w2[t];
    lags[t]   = slot + 1;
}

// ---- prep: zero blend buffers slot 0 (t=0 input state) ----
__global__ void prep_zero(float* __restrict__ hbf32, short* __restrict__ hbf16) {
    int i = blockIdx.x * blockDim.x + threadIdx.x;
    if (i < B_ * H_) { hbf32[i] = 0.f; hbf16[i] = 0; }
}

// ---- one recurrent step ----
// grid 64 x 256. WG owns h-cols [16*wg, 16*wg+16); computes gate rows j, H+j, 2H+j.
__global__ __launch_bounds__(256) void step_kernel(
    const short* __restrict__ Wcat, const short* __restrict__ xb,
    const float* __restrict__ b_ih, const float* __restrict__ b_hh,
    float* __restrict__ ring, float* __restrict__ hbf32, short* __restrict__ hbf16,
    const float* __restrict__ alphas, const float* __restrict__ betas,
    const int* __restrict__ lags, float* __restrict__ out, int t) {

    const int tid = threadIdx.x;
    const int w   = tid >> 6;     // wave 0..3
    const int l   = tid & 63;
    const int l15 = l & 15;
    const int lhi = l >> 4;       // 0..3
    const int c0  = blockIdx.x << 4;
    const int cur = t & 1, nxt = cur ^ 1;

    // K-split: wave0 = x phase [0,256); waves 1..3 split h phase [256,1280)
    int k_begin, k_iters;
    if      (w == 0) { k_begin = 0;   k_iters = 8;  }
    else if (w == 1) { k_begin = 256; k_iters = 11; }
    else if (w == 2) { k_begin = 608; k_iters = 11; }
    else             { k_begin = 960; k_iters = 10; }

    f32x4 acc[3][4];
    #pragma unroll
    for (int g = 0; g < 3; ++g)
        #pragma unroll
        for (int rt = 0; rt < 4; ++rt) acc[g][rt] = (f32x4){0.f, 0.f, 0.f, 0.f};

    const short* bp[3];
    #pragma unroll
    for (int g = 0; g < 3; ++g)
        bp[g] = Wcat + ((long)(g * H_ + c0 + l15) * KT_ + k_begin + lhi * 8);

    const short* ap[4];
    if (w == 0) {
        const short* xbase = xb + (long)t * (B_ * XD_);
        #pragma unroll
        for (int rt = 0; rt < 4; ++rt) ap[rt] = xbase + (rt * 16 + l15) * XD_ + lhi * 8;
    } else {
        const short* hbase = hbf16 + cur * (B_ * H_);
        #pragma unroll
        for (int rt = 0; rt < 4; ++rt)
            ap[rt] = hbase + (rt * 16 + l15) * H_ + (k_begin - 256) + lhi * 8;
    }

    for (int it = 0; it < k_iters; ++it) {
        bf16x8 bf[3], af[4];
        #pragma unroll
        for (int g = 0; g < 3; ++g) { bf[g] = *(const bf16x8*)bp[g]; bp[g] += 32; }
        #pragma unroll
        for (int rt = 0; rt < 4; ++rt) { af[rt] = *(const bf16x8*)ap[rt]; ap[rt] += 32; }
        #pragma unroll
        for (int g = 0; g < 3; ++g)
            #pragma unroll
            for (int rt = 0; rt < 4; ++rt)
                acc[g][rt] = __builtin_amdgcn_mfma_f32_16x16x32_bf16(af[rt], bf[g], acc[g][rt], 0, 0, 0);
    }

    // cross-wave K reduction in LDS: [wave][tile = g*4+rt][lane][4]
    __shared__ float lds[4 * 12 * 64 * 4];
    #pragma unroll
    for (int g = 0; g < 3; ++g)
        #pragma unroll
        for (int rt = 0; rt < 4; ++rt)
            *(f32x4*)&lds[((w * 12 + g * 4 + rt) * 64 + l) * 4] = acc[g][rt];
    __syncthreads();

    // epilogue: wave w takes row-tile rt = w
    const int jj = c0 + l15;
    const float bir = b_ih[jj],          bhr = b_hh[jj];
    const float biz = b_ih[H_ + jj],     bhz = b_hh[H_ + jj];
    const float bin = b_ih[2 * H_ + jj], bhn = b_hh[2 * H_ + jj];
    const float al  = alphas[t + 1];
    const float bet = betas[t + 1];
    const int   lg  = lags[t + 1];

    f32x4 X[3], Hs[3];
    #pragma unroll
    for (int g = 0; g < 3; ++g) {
        X[g] = *(const f32x4*)&lds[((0 * 12 + g * 4 + w) * 64 + l) * 4];
        f32x4 h1 = *(const f32x4*)&lds[((1 * 12 + g * 4 + w) * 64 + l) * 4];
        f32x4 h2 = *(const f32x4*)&lds[((2 * 12 + g * 4 + w) * 64 + l) * 4];
        f32x4 h3 = *(const f32x4*)&lds[((3 * 12 + g * 4 + w) * 64 + l) * 4];
        Hs[g] = h1 + h2 + h3;
    }

    float*       ringw = ring  + (long)(t & 15) * (B_ * H_);
    const float* hbcur = hbf32 + cur * (B_ * H_);
    float*       hbnx  = hbf32 + nxt * (B_ * H_);
    short*       h16nx = hbf16 + nxt * (B_ * H_);

    #pragma unroll
    for (int r = 0; r < 4; ++r) {
        const int  m   = w * 16 + lhi * 4 + r;        // batch row
        const long idx = (long)m * H_ + jj;
        float rg = sigm_(X[0][r] + Hs[0][r] + bir + bhr);
        float zg = sigm_(X[1][r] + Hs[1][r] + biz + bhz);
        float ng = tanh_(X[2][r] + bin + rg * (Hs[2][r] + bhn));
        float hb = hbcur[idx];
        float hn = (1.f - zg) * ng + zg * hb;
        ringw[idx] = hn;
        float sk = 0.f;
        if (bet != 0.f)
            sk = (lg == 1) ? hn : ring[(long)((t + 1 - lg) & 15) * (B_ * H_) + idx];
        float hbn = al * hn + bet * sk;
        hbnx[idx]  = hbn;
        h16nx[idx] = bf16_of(hbn);
        if (t == T_ - 1) out[idx] = 2.f * hn;
    }
}

extern "C" void kernel_launch(void* const* d_in, const int* in_sizes, int n_in,
                              void* d_out, int out_size, void* d_ws, size_t ws_size,
                              hipStream_t stream) {
    const float* x    = (const float*)d_in[0];
    const float* W_ih = (const float*)d_in[1];
    const float* W_hh = (const float*)d_in[2];
    const float* b_ih = (const float*)d_in[3];
    const float* b_hh = (const float*)d_in[4];
    const int*   w1   = (const int*)d_in[5];
    const int*   w2   = (const int*)d_in[6];
    const int*   ssp  = (const int*)d_in[7];
    float* out = (float*)d_out;

    char* ws = (char*)d_ws;
    short* Wcat   = (short*)(ws + OFF_WCAT);
    short* xb     = (short*)(ws + OFF_XB);
    float* ring   = (float*)(ws + OFF_RING);
    float* hbf32  = (float*)(ws + OFF_HBF32);
    short* hbf16  = (short*)(ws + OFF_HBF16);
    float* alphas = (float*)(ws + OFF_ALPHA);
    float* betas  = (float*)(ws + OFF_BETA);
    int*   lags   = (int*)(ws + OFF_LAG);

    prep_wcat<<<3072, 256, 0, stream>>>(W_ih, W_hh, Wcat);
    prep_xb<<<8192, 256, 0, stream>>>(x, xb);
    prep_plan<<<1, 1024, 0, stream>>>(w1, w2, ssp, alphas, betas, lags);
    prep_zero<<<64, 1024, 0, stream>>>(hbf32, hbf16);

    for (int t = 0; t < T_; ++t)
        step_kernel<<<64, 256, 0, stream>>>(Wcat, xb, b_ih, b_hh, ring, hbf32, hbf16,
                                            alphas, betas, lags, out, t);
}